// Round 4
// baseline (223.365 us; speedup 1.0000x reference)
//
#include <hip/hip_runtime.h>
#include <math.h>

// Problem constants
#define B_  8
#define D_  128
#define L_  2048
#define H_  8
#define DH_ 16

#define LOG2E 1.4426950408889634f

typedef __bf16 bf16x8 __attribute__((ext_vector_type(8)));
typedef float  floatx4 __attribute__((ext_vector_type(4)));
typedef float  floatx16 __attribute__((ext_vector_type(16)));

#if __has_builtin(__builtin_amdgcn_exp2f)
#define EXP2(x) __builtin_amdgcn_exp2f(x)
#else
#define EXP2(x) exp2f(x)
#endif

// tau: swap bits 2,3 of a row index (K A-frag row permutation, involution
// within each aligned 16-row group).
__device__ __forceinline__ int tau16(int x) {
  return (x & ~12) | ((x & 4) << 1) | ((x & 8) >> 1);
}

// ---------------------------------------------------------------------------
// Weight pre-convert: fp32 W -> bf16 MFMA frag layout (lane idx = col,
// k = quad*8+j). tiles 0..7 = Q heads (W_q pre-scaled by DH^-0.5 * log2e so
// attn softmax is exp2(s)), 8..15 = K, 16..23 = V.
// ---------------------------------------------------------------------------
__global__ __launch_bounds__(256) void wconv_kernel(
    const float* __restrict__ wmem, const float* __restrict__ wq,
    __bf16* __restrict__ Wb) {
  const int tile = blockIdx.x;
  const int tid = threadIdx.x;
  const int kc = tid >> 6, lane = tid & 63;
  const int quad = lane >> 4, col = lane & 15;
  const float* src;
  float scale = 1.0f;
  if (tile < 8) {
    src = wq + (tile * 16 + col) * D_;
    scale = 0.25f * LOG2E;  // DH^-0.5 and log2e folded into W_q
  } else if (tile < 16) {
    src = wmem + ((tile - 8) * 16 + col) * D_;
  } else {
    src = wmem + (128 + (tile - 16) * 16 + col) * D_;
  }
  const float* p = src + kc * 32 + quad * 8;
  bf16x8 w;
#pragma unroll
  for (int j = 0; j < 8; ++j) w[j] = (__bf16)(p[j] * scale);
  *(bf16x8*)(Wb + ((size_t)((tile * 4 + kc) * 64) + lane) * 8) = w;
}

// ---------------------------------------------------------------------------
// Mask prefix scan: per batch b, sel[b][p] = l of the p-th unmasked key,
// cnt[b] = number of unmasked keys. One block per b.
// ---------------------------------------------------------------------------
__global__ __launch_bounds__(256) void scan_kernel(
    const int* __restrict__ mask, int* __restrict__ sel,
    int* __restrict__ cnt) {
  __shared__ int tsum[256];
  __shared__ int tbase[256];
  const int b = blockIdx.x, tid = threadIdx.x;
  int m[8], s = 0;
  const int* mp = mask + b * L_ + tid * 8;
#pragma unroll
  for (int j = 0; j < 8; ++j) { m[j] = mp[j]; s += m[j]; }
  tsum[tid] = s;
  __syncthreads();
  if (tid == 0) {
    int a = 0;
#pragma unroll 1
    for (int i = 0; i < 256; ++i) { tbase[i] = a; a += tsum[i]; }
    cnt[b] = a;
  }
  __syncthreads();
  int p = tbase[tid];
  int* sb = sel + b * L_;
#pragma unroll
  for (int j = 0; j < 8; ++j) {
    if (m[j]) sb[p++] = tid * 8 + j;
  }
}

// ---------------------------------------------------------------------------
// Projection v2 (round-3, unchanged): MFMA -> LDS staging -> coalesced
// bf16x8 stores. Qs natural; Ks tau-permuted; V^T with mask folded.
// ---------------------------------------------------------------------------
__global__ __launch_bounds__(256) void proj_kernel(
    const float* __restrict__ qin, const int* __restrict__ mask,
    const __bf16* __restrict__ Wb, __bf16* __restrict__ Qs,
    __bf16* __restrict__ Ks, __bf16* __restrict__ Vp) {
  __shared__ float xl[16][132];        // row stride >= 128 (D)!
  __shared__ __bf16 Qst[8][16][16];    // [head][l-row][col]
  __shared__ __bf16 Kst[8][16][16];    // [head][tau-permuted l-row][col]
  __shared__ __bf16 Vst[8][17][16];    // [head][dh-row 0-15, mask row 16][l-col]
  const int b = blockIdx.x >> 7;
  const int l0 = (blockIdx.x & 127) * 16;
  const int tid = threadIdx.x;

#pragma unroll
  for (int i = 0; i < 2; ++i) {
    int idx = i * 256 + tid;
    int d = idx >> 2;
    int l4 = (idx & 3) * 4;
    const float4 v = *(const float4*)&qin[(b * D_ + d) * L_ + l0 + l4];
    xl[l4 + 0][d] = v.x;
    xl[l4 + 1][d] = v.y;
    xl[l4 + 2][d] = v.z;
    xl[l4 + 3][d] = v.w;
  }

  // Mask row 16 of each head's Vst tile for our 16 columns.
  if (tid < 128) {
    const int hh = tid >> 4, c = tid & 15;
    Vst[hh][16][c] = (__bf16)(float)mask[b * L_ + l0 + c];
  }
  __syncthreads();

  const int lane = tid & 63, wave = tid >> 6;
  const int quad = lane >> 4, col = lane & 15;

  bf16x8 af[4];
#pragma unroll
  for (int kc = 0; kc < 4; ++kc) {
    const float* s = &xl[col][kc * 32 + quad * 8];
#pragma unroll
    for (int j = 0; j < 8; ++j) af[kc][j] = (__bf16)s[j];
  }

  const int quadK = ((quad & 1) << 1) | (quad >> 1);     // tau: swap bits 2,3
  const float mvv = (float)mask[b * L_ + l0 + col];      // V column mask

#pragma unroll
  for (int tt = 0; tt < 6; ++tt) {
    const int tile = wave * 6 + tt;
    floatx4 acc = {0.f, 0.f, 0.f, 0.f};
    const bool isV = (tile >= 16);
#pragma unroll
    for (int kc = 0; kc < 4; ++kc) {
      bf16x8 wf =
          *(const bf16x8*)(Wb + ((size_t)((tile * 4 + kc) * 64) + lane) * 8);
      acc = isV ? __builtin_amdgcn_mfma_f32_16x16x32_bf16(wf, af[kc], acc, 0, 0, 0)
                : __builtin_amdgcn_mfma_f32_16x16x32_bf16(af[kc], wf, acc, 0, 0, 0);
    }
    if (tile < 8) {  // Q head -> LDS
#pragma unroll
      for (int r = 0; r < 4; ++r) Qst[tile][quad * 4 + r][col] = (__bf16)acc[r];
    } else if (tile < 16) {  // K head, tau-permuted rows -> LDS
#pragma unroll
      for (int r = 0; r < 4; ++r)
        Kst[tile - 8][quadK * 4 + r][col] = (__bf16)acc[r];
    } else {  // V^T * mask -> LDS
#pragma unroll
      for (int r = 0; r < 4; ++r)
        Vst[tile - 16][quad * 4 + r][col] = (__bf16)(acc[r] * mvv);
    }
  }
  __syncthreads();

  // Cooperative coalesced stores.
  {
    const int hID = tid >> 5;           // 0..7
    const int u = tid & 31;             // 0..31
    const int row = u >> 1, ch = (u & 1) * 8;
    const size_t bhq = (size_t)(b * H_ + hID);
    bf16x8 qv = *(const bf16x8*)&Qst[hID][row][ch];
    *(bf16x8*)(Qs + (bhq * L_ + l0 + row) * DH_ + ch) = qv;
    bf16x8 kv = *(const bf16x8*)&Kst[hID][row][ch];
    *(bf16x8*)(Ks + (bhq * L_ + l0 + row) * DH_ + ch) = kv;
  }
  // V: 8 heads x 17 rows x 2 halves = 272 16B units.
#pragma unroll
  for (int pass = 0; pass < 2; ++pass) {
    const int u = pass * 256 + tid;
    if (u < 272) {
      const int hID = u / 34;
      const int w = u - hID * 34;
      const int row = w >> 1, ch = (w & 1) * 8;
      bf16x8 vv = *(const bf16x8*)&Vst[hID][row][ch];
      __bf16* dst = Vp +
          (((size_t)(b * H_ + hID) * 64 + (l0 >> 5)) * 32 + row) * 32 +
          (l0 & 31) + ch;
      *(bf16x8*)dst = vv;
    }
  }
}

// ---------------------------------------------------------------------------
// Key compaction: gather unmasked keys of dense Ks/Vp into Ksc/Vpc.
//   Masked keys contribute exactly 0 to numerator (V col zeroed) and
//   denominator (mask row 0) -> dropping them is exact. Last partial tile
//   zero-padded: K=0 -> exp2(0)=1 x V=0, mask-row 0 -> contributes 0.
//   tau permute preserved: dense row tau16(l) -> compacted row tau16(p).
// grid = B*H*8 segments x 256 threads (one p per thread).
// ---------------------------------------------------------------------------
__global__ __launch_bounds__(256) void compact_kernel(
    const int* __restrict__ sel, const int* __restrict__ cnt,
    const __bf16* __restrict__ Ks, const __bf16* __restrict__ Vp,
    __bf16* __restrict__ Ksc, __bf16* __restrict__ Vpc) {
  const int blk = blockIdx.x;
  const int seg = blk & 7;
  const int bh = blk >> 3;
  const int b = bh >> 3;
  const int cn = cnt[b];
  const int pend = ((cn + 31) >> 5) << 5;  // zero-pad bound (32-aligned)
  const int p = seg * 256 + (int)threadIdx.x;
  if (p >= pend) return;
  const size_t bhb = (size_t)bh;
  const int sp = tau16(p);
  bf16x8* kdst = (bf16x8*)(Ksc + (bhb * L_ + sp) * DH_);
  __bf16* vdst = Vpc + ((bhb * 64 + (p >> 5)) * 32) * 32 + (p & 31);
  if (p < cn) {
    const int l = sel[b * L_ + p];
    const int sl = tau16(l);
    const bf16x8* ksrc = (const bf16x8*)(Ks + (bhb * L_ + sl) * DH_);
    kdst[0] = ksrc[0];
    kdst[1] = ksrc[1];
    const __bf16* vsrc = Vp + ((bhb * 64 + (l >> 5)) * 32) * 32 + (l & 31);
#pragma unroll
    for (int r = 0; r < 16; ++r) vdst[r * 32] = vsrc[r * 32];
    vdst[16 * 32] = (__bf16)1.0f;  // mask row: every compacted key is real
  } else {
    bf16x8 z = {};
    kdst[0] = z;
    kdst[1] = z;
#pragma unroll
    for (int r = 0; r <= 16; ++r) vdst[r * 32] = (__bf16)0.0f;
  }
}

// ---------------------------------------------------------------------------
// Attention v12 = v11 (dual-q, K-split wave pairs, XCD remap, top-issued
// prefetch) over COMPACTED keys: nt = ceil(cnt[b]/32) ~ 32-33 tiles instead
// of 64 -> exp/MFMA/load work all halve.
//   Post-mortem v8-v11: efficiency-side restructures moved attn only
//   50->~40us; ~50% of keys are masked and were computed anyway. Compaction
//   halves the WORK, robust to which micro-pipe binds.
// grid = B*H*(L/128) = 1024 blocks x 4 waves (wave: 64 q x ~16 kv-tiles).
// ---------------------------------------------------------------------------
__global__ __launch_bounds__(256, 4) void attn_kernel(
    const __bf16* __restrict__ Qs, const __bf16* __restrict__ Ks,
    const __bf16* __restrict__ Vp, const int* __restrict__ cnt,
    float* __restrict__ out) {
  __shared__ float red[2][64][33];  // 32 parked floats/lane, pad stride 33
  const int idx = blockIdx.x;
  const int qb = idx >> 6;        // 16 q-blocks of 128 rows
  const int bhi = idx & 63;       // bh minor -> idx%8 = h fixed per bh (XCD)
  const int h = bhi & 7;
  const int b = bhi >> 3;
  const int tid = threadIdx.x;
  const int lane = tid & 63, wave = tid >> 6;
  const int pair = wave >> 1;     // which 64 q-rows of this block
  const int half = wave & 1;      // which chunk of KV tiles
  const int n = lane & 31, hh = lane >> 5;
  const int q0 = qb * 128 + pair * 64;
  const size_t bh = (size_t)(b * H_ + h);

  // dynamic tile range: [tb, tb+ntw) of nt = ceil(cnt/32) compacted tiles
  const int cn = cnt[b];
  const int nt = (cn + 31) >> 5;
  const int nh0 = (nt + 1) >> 1;
  const int tb = half ? nh0 : 0;
  const int ntw = half ? (nt - nh0) : nh0;

  // Q B-frags: B[k=dh=8*hh+j][n=q] for q-rows q0+n and q0+32+n
  const bf16x8 qf0 = *(const bf16x8*)(Qs + (bh * L_ + q0 + n) * DH_ + 8 * hh);
  const bf16x8 qf1 =
      *(const bf16x8*)(Qs + (bh * L_ + q0 + 32 + n) * DH_ + 8 * hh);

  const __bf16* Kp = Ks + bh * L_ * DH_ + (size_t)n * DH_ + 8 * hh +
                     (size_t)tb * 32 * DH_;
  const __bf16* Vq = Vp + (bh * 64 * 32 + (size_t)n) * 32 + 8 * hh +
                     (size_t)tb * 1024;

  floatx16 acc0, acc1;
#pragma unroll
  for (int r = 0; r < 16; ++r) { acc0[r] = 0.f; acc1[r] = 0.f; }
  const floatx16 zz = acc0;

  // prologue: first tile of this wave's range into buffer 0
  bf16x8 kf[2], va[2], vb[2];
  kf[0] = *(const bf16x8*)(Kp);
  va[0] = *(const bf16x8*)(Vq);
  vb[0] = *(const bf16x8*)(Vq + 16);

#pragma unroll 2
  for (int t = 0; t < ntw; ++t) {
    const int cur = t & 1, nxt = cur ^ 1;
    // issue next-tile loads FIRST: load->use distance = one full body.
    const int tn = (t + 1 < ntw) ? t + 1 : t;
    kf[nxt] = *(const bf16x8*)(Kp + (size_t)tn * 32 * DH_);
    va[nxt] = *(const bf16x8*)(Vq + (size_t)tn * 1024);
    vb[nxt] = *(const bf16x8*)(Vq + (size_t)tn * 1024 + 16);
    // S^T for both q-groups (32 keys x 32 q each), C = 0
    floatx16 s0 = __builtin_amdgcn_mfma_f32_32x32x16_bf16(kf[cur], qf0, zz, 0, 0, 0);
    floatx16 s1 = __builtin_amdgcn_mfma_f32_32x32x16_bf16(kf[cur], qf1, zz, 0, 0, 0);
    // P^T = exp2(S^T): packed pairs are exactly the PV B-frags
    bf16x8 pA0, pB0, pA1, pB1;
#pragma unroll
    for (int j = 0; j < 8; ++j) pA0[j] = (__bf16)EXP2(s0[j]);
#pragma unroll
    for (int j = 0; j < 8; ++j) pB0[j] = (__bf16)EXP2(s0[8 + j]);
#pragma unroll
    for (int j = 0; j < 8; ++j) pA1[j] = (__bf16)EXP2(s1[j]);
#pragma unroll
    for (int j = 0; j < 8; ++j) pB1[j] = (__bf16)EXP2(s1[8 + j]);
    // PV: the SAME V tile feeds both q-groups
    acc0 = __builtin_amdgcn_mfma_f32_32x32x16_bf16(va[cur], pA0, acc0, 0, 0, 0);
    acc0 = __builtin_amdgcn_mfma_f32_32x32x16_bf16(vb[cur], pB0, acc0, 0, 0, 0);
    acc1 = __builtin_amdgcn_mfma_f32_32x32x16_bf16(va[cur], pA1, acc1, 0, 0, 0);
    acc1 = __builtin_amdgcn_mfma_f32_32x32x16_bf16(vb[cur], pB1, acc1, 0, 0, 0);
  }

  // cross-wave K-reduction: half 0 parks both partial accs, half 1 sums.
  if (half == 0) {
#pragma unroll
    for (int r = 0; r < 16; ++r) {
      red[pair][lane][r] = acc0[r];
      red[pair][lane][16 + r] = acc1[r];
    }
  }
  __syncthreads();
  if (half == 0) return;
#pragma unroll
  for (int r = 0; r < 16; ++r) {
    acc0[r] += red[pair][lane][r];
    acc1[r] += red[pair][lane][16 + r];
  }

  // l = row 16 of O^T = acc reg 8 on the hh==0 half; broadcast to hh==1.
  float l0v = acc0[8];
  float l0o = __shfl_xor(l0v, 32, 64);
  float inv0 = __builtin_amdgcn_rcpf(hh ? l0o : l0v);
  float l1v = acc1[8];
  float l1o = __shfl_xor(l1v, 32, 64);
  float inv1 = __builtin_amdgcn_rcpf(hh ? l1o : l1v);

  // regs 0-7 are the 8 valid dh rows for this half: dh = (r&3)+8*(r>>2)+4*hh
  float* obase = out + ((size_t)(b * D_ + h * DH_)) * L_ + q0 + n;
#pragma unroll
  for (int r = 0; r < 8; ++r) {
    const int dh = (r & 3) + 8 * (r >> 2) + 4 * hh;
    obase[(size_t)dh * L_] = acc0[r] * inv0;
    obase[(size_t)dh * L_ + 32] = acc1[r] * inv1;
  }
}

// ---------------------------------------------------------------------------
extern "C" void kernel_launch(void* const* d_in, const int* in_sizes, int n_in,
                              void* d_out, int out_size, void* d_ws,
                              size_t ws_size, hipStream_t stream) {
  const float* queries = (const float*)d_in[0];  // [B, D, L] fp32
  const int*   mask    = (const int*)d_in[1];    // [B, L] int32
  const float* wmem    = (const float*)d_in[2];  // [2D, D] fp32
  const float* wq      = (const float*)d_in[3];  // [D, D] fp32
  float* out = (float*)d_out;                    // [B, D, L] fp32

  // Workspace layout (MiB offsets):
  //   0: Qs (4) | 4: Ks dense (4) | 8: Vp dense (8) | 16: Ksc (4) |
  //   20: Vpc (8) | 28: sel [B][L] int (64KB) + cnt [B] int
  const size_t SEG = (size_t)B_ * H_ * L_ * DH_ * sizeof(__bf16);
  __bf16* Qs  = (__bf16*)d_ws;
  __bf16* Ks  = (__bf16*)((char*)d_ws + SEG);
  __bf16* Vp  = (__bf16*)((char*)d_ws + 2 * SEG);
  __bf16* Ksc = (__bf16*)((char*)d_ws + 4 * SEG);
  __bf16* Vpc = (__bf16*)((char*)d_ws + 5 * SEG);
  int* sel = (int*)((char*)d_ws + 7 * SEG);
  int* cnt = sel + B_ * L_;

  // Wb (96 KiB) in d_out scratch: wconv writes, proj reads, attn then
  // overwrites ALL of d_out — stream-ordered, race-free.
  __bf16* Wb = (__bf16*)((char*)d_out + (4u << 20));

  scan_kernel<<<B_, 256, 0, stream>>>(mask, sel, cnt);
  wconv_kernel<<<24, 256, 0, stream>>>(wmem, wq, Wb);
  proj_kernel<<<B_ * (L_ / 16), 256, 0, stream>>>(queries, mask, Wb, Qs, Ks, Vp);
  compact_kernel<<<B_ * H_ * 8, 256, 0, stream>>>(sel, cnt, Ks, Vp, Ksc, Vpc);
  attn_kernel<<<B_ * H_ * (L_ / 128), 256, 0, stream>>>(Qs, Ksc, Vpc, cnt, out);
}

// Round 5
// 117.672 us; speedup vs baseline: 1.8982x; 1.8982x over previous
//
#include <hip/hip_runtime.h>
#include <math.h>

// Problem constants
#define B_  8
#define D_  128
#define L_  2048
#define H_  8
#define DH_ 16

#define LOG2E 1.4426950408889634f

typedef __bf16 bf16x8 __attribute__((ext_vector_type(8)));
typedef float  floatx4 __attribute__((ext_vector_type(4)));
typedef float  floatx16 __attribute__((ext_vector_type(16)));

#if __has_builtin(__builtin_amdgcn_exp2f)
#define EXP2(x) __builtin_amdgcn_exp2f(x)
#else
#define EXP2(x) exp2f(x)
#endif

// tau: swap bits 2,3 of a row index (K A-frag row permutation, involution
// within each aligned 16-row group).
__device__ __forceinline__ int tau16(int x) {
  return (x & ~12) | ((x & 4) << 1) | ((x & 8) >> 1);
}

// ---------------------------------------------------------------------------
// Weight pre-convert: fp32 W -> bf16 MFMA frag layout (lane idx = col,
// k = quad*8+j). tiles 0..7 = Q heads (W_q pre-scaled by DH^-0.5 * log2e so
// attn softmax is exp2(s)), 8..15 = K, 16..23 = V.
// ---------------------------------------------------------------------------
__global__ __launch_bounds__(256) void wconv_kernel(
    const float* __restrict__ wmem, const float* __restrict__ wq,
    __bf16* __restrict__ Wb) {
  const int tile = blockIdx.x;
  const int tid = threadIdx.x;
  const int kc = tid >> 6, lane = tid & 63;
  const int quad = lane >> 4, col = lane & 15;
  const float* src;
  float scale = 1.0f;
  if (tile < 8) {
    src = wq + (tile * 16 + col) * D_;
    scale = 0.25f * LOG2E;  // DH^-0.5 and log2e folded into W_q
  } else if (tile < 16) {
    src = wmem + ((tile - 8) * 16 + col) * D_;
  } else {
    src = wmem + (128 + (tile - 16) * 16 + col) * D_;
  }
  const float* p = src + kc * 32 + quad * 8;
  bf16x8 w;
#pragma unroll
  for (int j = 0; j < 8; ++j) w[j] = (__bf16)(p[j] * scale);
  *(bf16x8*)(Wb + ((size_t)((tile * 4 + kc) * 64) + lane) * 8) = w;
}

// ---------------------------------------------------------------------------
// Mask prefix scan: per batch b, sel[b][p] = l of the p-th unmasked key,
// cnt[b] = number of unmasked keys. One block per b.
// ---------------------------------------------------------------------------
__global__ __launch_bounds__(256) void scan_kernel(
    const int* __restrict__ mask, int* __restrict__ sel,
    int* __restrict__ cnt) {
  __shared__ int tsum[256];
  __shared__ int tbase[256];
  const int b = blockIdx.x, tid = threadIdx.x;
  int m[8], s = 0;
  const int* mp = mask + b * L_ + tid * 8;
#pragma unroll
  for (int j = 0; j < 8; ++j) { m[j] = mp[j]; s += m[j]; }
  tsum[tid] = s;
  __syncthreads();
  if (tid == 0) {
    int a = 0;
#pragma unroll 1
    for (int i = 0; i < 256; ++i) { tbase[i] = a; a += tsum[i]; }
    cnt[b] = a;
  }
  __syncthreads();
  int p = tbase[tid];
  int* sb = sel + b * L_;
#pragma unroll
  for (int j = 0; j < 8; ++j) {
    if (m[j]) sb[p++] = tid * 8 + j;
  }
}

// ---------------------------------------------------------------------------
// Projection v2 (round-3, unchanged): MFMA -> LDS staging -> coalesced
// bf16x8 stores. Qs natural; Ks tau-permuted; V^T with mask folded.
// ---------------------------------------------------------------------------
__global__ __launch_bounds__(256) void proj_kernel(
    const float* __restrict__ qin, const int* __restrict__ mask,
    const __bf16* __restrict__ Wb, __bf16* __restrict__ Qs,
    __bf16* __restrict__ Ks, __bf16* __restrict__ Vp) {
  __shared__ float xl[16][132];        // row stride >= 128 (D)!
  __shared__ __bf16 Qst[8][16][16];    // [head][l-row][col]
  __shared__ __bf16 Kst[8][16][16];    // [head][tau-permuted l-row][col]
  __shared__ __bf16 Vst[8][17][16];    // [head][dh-row 0-15, mask row 16][l-col]
  const int b = blockIdx.x >> 7;
  const int l0 = (blockIdx.x & 127) * 16;
  const int tid = threadIdx.x;

#pragma unroll
  for (int i = 0; i < 2; ++i) {
    int idx = i * 256 + tid;
    int d = idx >> 2;
    int l4 = (idx & 3) * 4;
    const float4 v = *(const float4*)&qin[(b * D_ + d) * L_ + l0 + l4];
    xl[l4 + 0][d] = v.x;
    xl[l4 + 1][d] = v.y;
    xl[l4 + 2][d] = v.z;
    xl[l4 + 3][d] = v.w;
  }

  // Mask row 16 of each head's Vst tile for our 16 columns.
  if (tid < 128) {
    const int hh = tid >> 4, c = tid & 15;
    Vst[hh][16][c] = (__bf16)(float)mask[b * L_ + l0 + c];
  }
  __syncthreads();

  const int lane = tid & 63, wave = tid >> 6;
  const int quad = lane >> 4, col = lane & 15;

  bf16x8 af[4];
#pragma unroll
  for (int kc = 0; kc < 4; ++kc) {
    const float* s = &xl[col][kc * 32 + quad * 8];
#pragma unroll
    for (int j = 0; j < 8; ++j) af[kc][j] = (__bf16)s[j];
  }

  const int quadK = ((quad & 1) << 1) | (quad >> 1);     // tau: swap bits 2,3
  const float mvv = (float)mask[b * L_ + l0 + col];      // V column mask

#pragma unroll
  for (int tt = 0; tt < 6; ++tt) {
    const int tile = wave * 6 + tt;
    floatx4 acc = {0.f, 0.f, 0.f, 0.f};
    const bool isV = (tile >= 16);
#pragma unroll
    for (int kc = 0; kc < 4; ++kc) {
      bf16x8 wf =
          *(const bf16x8*)(Wb + ((size_t)((tile * 4 + kc) * 64) + lane) * 8);
      acc = isV ? __builtin_amdgcn_mfma_f32_16x16x32_bf16(wf, af[kc], acc, 0, 0, 0)
                : __builtin_amdgcn_mfma_f32_16x16x32_bf16(af[kc], wf, acc, 0, 0, 0);
    }
    if (tile < 8) {  // Q head -> LDS
#pragma unroll
      for (int r = 0; r < 4; ++r) Qst[tile][quad * 4 + r][col] = (__bf16)acc[r];
    } else if (tile < 16) {  // K head, tau-permuted rows -> LDS
#pragma unroll
      for (int r = 0; r < 4; ++r)
        Kst[tile - 8][quadK * 4 + r][col] = (__bf16)acc[r];
    } else {  // V^T * mask -> LDS
#pragma unroll
      for (int r = 0; r < 4; ++r)
        Vst[tile - 16][quad * 4 + r][col] = (__bf16)(acc[r] * mvv);
    }
  }
  __syncthreads();

  // Cooperative coalesced stores.
  {
    const int hID = tid >> 5;           // 0..7
    const int u = tid & 31;             // 0..31
    const int row = u >> 1, ch = (u & 1) * 8;
    const size_t bhq = (size_t)(b * H_ + hID);
    bf16x8 qv = *(const bf16x8*)&Qst[hID][row][ch];
    *(bf16x8*)(Qs + (bhq * L_ + l0 + row) * DH_ + ch) = qv;
    bf16x8 kv = *(const bf16x8*)&Kst[hID][row][ch];
    *(bf16x8*)(Ks + (bhq * L_ + l0 + row) * DH_ + ch) = kv;
  }
  // V: 8 heads x 17 rows x 2 halves = 272 16B units.
#pragma unroll
  for (int pass = 0; pass < 2; ++pass) {
    const int u = pass * 256 + tid;
    if (u < 272) {
      const int hID = u / 34;
      const int w = u - hID * 34;
      const int row = w >> 1, ch = (w & 1) * 8;
      bf16x8 vv = *(const bf16x8*)&Vst[hID][row][ch];
      __bf16* dst = Vp +
          (((size_t)(b * H_ + hID) * 64 + (l0 >> 5)) * 32 + row) * 32 +
          (l0 & 31) + ch;
      *(bf16x8*)dst = vv;
    }
  }
}

// ---------------------------------------------------------------------------
// Key compaction (round-4, unchanged): gather unmasked keys of dense Ks/Vp
// into Ksc/Vpc. Exact: masked keys contribute 0 to numerator and
// denominator; zero-padded tail tiles contribute 0 likewise.
// ---------------------------------------------------------------------------
__global__ __launch_bounds__(256) void compact_kernel(
    const int* __restrict__ sel, const int* __restrict__ cnt,
    const __bf16* __restrict__ Ks, const __bf16* __restrict__ Vp,
    __bf16* __restrict__ Ksc, __bf16* __restrict__ Vpc) {
  const int blk = blockIdx.x;
  const int seg = blk & 7;
  const int bh = blk >> 3;
  const int b = bh >> 3;
  const int cn = cnt[b];
  const int pend = ((cn + 31) >> 5) << 5;  // zero-pad bound (32-aligned)
  const int p = seg * 256 + (int)threadIdx.x;
  if (p >= pend) return;
  const size_t bhb = (size_t)bh;
  const int sp = tau16(p);
  bf16x8* kdst = (bf16x8*)(Ksc + (bhb * L_ + sp) * DH_);
  __bf16* vdst = Vpc + ((bhb * 64 + (p >> 5)) * 32) * 32 + (p & 31);
  if (p < cn) {
    const int l = sel[b * L_ + p];
    const int sl = tau16(l);
    const bf16x8* ksrc = (const bf16x8*)(Ks + (bhb * L_ + sl) * DH_);
    kdst[0] = ksrc[0];
    kdst[1] = ksrc[1];
    const __bf16* vsrc = Vp + ((bhb * 64 + (l >> 5)) * 32) * 32 + (l & 31);
#pragma unroll
    for (int r = 0; r < 16; ++r) vdst[r * 32] = vsrc[r * 32];
    vdst[16 * 32] = (__bf16)1.0f;  // mask row: every compacted key is real
  } else {
    bf16x8 z = {};
    kdst[0] = z;
    kdst[1] = z;
#pragma unroll
    for (int r = 0; r <= 16; ++r) vdst[r * 32] = (__bf16)0.0f;
  }
}

// ---------------------------------------------------------------------------
// Attention v13 = v12's compacted-key algorithm, STATICALLY-INDEXED pipeline.
//   Post-mortem v12: dynamic trip count + kf[cur] array indexing -> the
//   unroll-2 epilogue iteration has runtime cur -> compiler demotes the
//   whole double-buffer arrays to SCRATCH (rule: runtime-indexed ext_vector
//   arrays). VGPR 256, occupancy 2/SIMD, VALUBusy 72% of 137us = spill
//   traffic. Fix: hand-written 2-stage pipeline with NAMED buffers
//   (kA/vaA/vbA, kB/vaB/vbB), t+=2 loop + static odd-tail. Every register
//   reference compile-time resolved; prefetch distance preserved.
// grid = B*H*(L/128) = 1024 blocks x 4 waves (wave: 64 q x ~16 kv-tiles).
// ---------------------------------------------------------------------------
__global__ __launch_bounds__(256, 4) void attn_kernel(
    const __bf16* __restrict__ Qs, const __bf16* __restrict__ Ks,
    const __bf16* __restrict__ Vp, const int* __restrict__ cnt,
    float* __restrict__ out) {
  __shared__ float red[2][64][33];  // 32 parked floats/lane, pad stride 33
  const int idx = blockIdx.x;
  const int qb = idx >> 6;        // 16 q-blocks of 128 rows
  const int bhi = idx & 63;       // bh minor -> idx%8 = h fixed per bh (XCD)
  const int h = bhi & 7;
  const int b = bhi >> 3;
  const int tid = threadIdx.x;
  const int lane = tid & 63, wave = tid >> 6;
  const int pair = wave >> 1;     // which 64 q-rows of this block
  const int half = wave & 1;      // which chunk of KV tiles
  const int n = lane & 31, hh = lane >> 5;
  const int q0 = qb * 128 + pair * 64;
  const size_t bh = (size_t)(b * H_ + h);

  // dynamic tile range: [tb, tb+ntw) of nt = ceil(cnt/32) compacted tiles
  const int cn = cnt[b];
  const int nt = (cn + 31) >> 5;
  const int nh0 = (nt + 1) >> 1;
  const int tb = half ? nh0 : 0;
  const int ntw = half ? (nt - nh0) : nh0;

  // Q B-frags: B[k=dh=8*hh+j][n=q] for q-rows q0+n and q0+32+n
  const bf16x8 qf0 = *(const bf16x8*)(Qs + (bh * L_ + q0 + n) * DH_ + 8 * hh);
  const bf16x8 qf1 =
      *(const bf16x8*)(Qs + (bh * L_ + q0 + 32 + n) * DH_ + 8 * hh);

  const __bf16* Kp = Ks + bh * L_ * DH_ + (size_t)n * DH_ + 8 * hh +
                     (size_t)tb * 32 * DH_;
  const __bf16* Vq = Vp + (bh * 64 * 32 + (size_t)n) * 32 + 8 * hh +
                     (size_t)tb * 1024;

  floatx16 acc0, acc1;
#pragma unroll
  for (int r = 0; r < 16; ++r) { acc0[r] = 0.f; acc1[r] = 0.f; }
  const floatx16 zz = acc0;

  // one KV tile against both q-groups; all operands are named registers.
  auto compute = [&](const bf16x8& KF, const bf16x8& VA, const bf16x8& VB) {
    floatx16 s0 = __builtin_amdgcn_mfma_f32_32x32x16_bf16(KF, qf0, zz, 0, 0, 0);
    floatx16 s1 = __builtin_amdgcn_mfma_f32_32x32x16_bf16(KF, qf1, zz, 0, 0, 0);
    bf16x8 pA0, pB0, pA1, pB1;
#pragma unroll
    for (int j = 0; j < 8; ++j) pA0[j] = (__bf16)EXP2(s0[j]);
#pragma unroll
    for (int j = 0; j < 8; ++j) pB0[j] = (__bf16)EXP2(s0[8 + j]);
#pragma unroll
    for (int j = 0; j < 8; ++j) pA1[j] = (__bf16)EXP2(s1[j]);
#pragma unroll
    for (int j = 0; j < 8; ++j) pB1[j] = (__bf16)EXP2(s1[8 + j]);
    acc0 = __builtin_amdgcn_mfma_f32_32x32x16_bf16(VA, pA0, acc0, 0, 0, 0);
    acc0 = __builtin_amdgcn_mfma_f32_32x32x16_bf16(VB, pB0, acc0, 0, 0, 0);
    acc1 = __builtin_amdgcn_mfma_f32_32x32x16_bf16(VA, pA1, acc1, 0, 0, 0);
    acc1 = __builtin_amdgcn_mfma_f32_32x32x16_bf16(VB, pB1, acc1, 0, 0, 0);
  };

  // prologue: tile 0 of this wave's range into stage A
  bf16x8 kA = *(const bf16x8*)(Kp);
  bf16x8 vaA = *(const bf16x8*)(Vq);
  bf16x8 vbA = *(const bf16x8*)(Vq + 16);
  bf16x8 kB, vaB, vbB;

  int t = 0;
#pragma unroll 1
  for (; t + 2 <= ntw; t += 2) {
    // load tile t+1 into B (consumed after compute(A) -> latency hidden)
    kB  = *(const bf16x8*)(Kp + (size_t)(t + 1) * 32 * DH_);
    vaB = *(const bf16x8*)(Vq + (size_t)(t + 1) * 1024);
    vbB = *(const bf16x8*)(Vq + (size_t)(t + 1) * 1024 + 16);
    compute(kA, vaA, vbA);
    // load tile t+2 into A (guarded: redundant in-bounds reload at range end)
    const size_t t2 = (size_t)((t + 2 < ntw) ? t + 2 : t + 1);
    kA  = *(const bf16x8*)(Kp + t2 * 32 * DH_);
    vaA = *(const bf16x8*)(Vq + t2 * 1024);
    vbA = *(const bf16x8*)(Vq + t2 * 1024 + 16);
    compute(kB, vaB, vbB);
  }
  if (t < ntw) {  // odd tail: last tile already resident in A
    compute(kA, vaA, vbA);
  }

  // cross-wave K-reduction: half 0 parks both partial accs, half 1 sums.
  if (half == 0) {
#pragma unroll
    for (int r = 0; r < 16; ++r) {
      red[pair][lane][r] = acc0[r];
      red[pair][lane][16 + r] = acc1[r];
    }
  }
  __syncthreads();
  if (half == 0) return;
#pragma unroll
  for (int r = 0; r < 16; ++r) {
    acc0[r] += red[pair][lane][r];
    acc1[r] += red[pair][lane][16 + r];
  }

  // l = row 16 of O^T = acc reg 8 on the hh==0 half; broadcast to hh==1.
  float l0v = acc0[8];
  float l0o = __shfl_xor(l0v, 32, 64);
  float inv0 = __builtin_amdgcn_rcpf(hh ? l0o : l0v);
  float l1v = acc1[8];
  float l1o = __shfl_xor(l1v, 32, 64);
  float inv1 = __builtin_amdgcn_rcpf(hh ? l1o : l1v);

  // regs 0-7 are the 8 valid dh rows for this half: dh = (r&3)+8*(r>>2)+4*hh
  float* obase = out + ((size_t)(b * D_ + h * DH_)) * L_ + q0 + n;
#pragma unroll
  for (int r = 0; r < 8; ++r) {
    const int dh = (r & 3) + 8 * (r >> 2) + 4 * hh;
    obase[(size_t)dh * L_] = acc0[r] * inv0;
    obase[(size_t)dh * L_ + 32] = acc1[r] * inv1;
  }
}

// ---------------------------------------------------------------------------
extern "C" void kernel_launch(void* const* d_in, const int* in_sizes, int n_in,
                              void* d_out, int out_size, void* d_ws,
                              size_t ws_size, hipStream_t stream) {
  const float* queries = (const float*)d_in[0];  // [B, D, L] fp32
  const int*   mask    = (const int*)d_in[1];    // [B, L] int32
  const float* wmem    = (const float*)d_in[2];  // [2D, D] fp32
  const float* wq      = (const float*)d_in[3];  // [D, D] fp32
  float* out = (float*)d_out;                    // [B, D, L] fp32

  // Workspace layout (MiB offsets):
  //   0: Qs (4) | 4: Ks dense (4) | 8: Vp dense (8) | 16: Ksc (4) |
  //   20: Vpc (8) | 28: sel [B][L] int (64KB) + cnt [B] int
  const size_t SEG = (size_t)B_ * H_ * L_ * DH_ * sizeof(__bf16);
  __bf16* Qs  = (__bf16*)d_ws;
  __bf16* Ks  = (__bf16*)((char*)d_ws + SEG);
  __bf16* Vp  = (__bf16*)((char*)d_ws + 2 * SEG);
  __bf16* Ksc = (__bf16*)((char*)d_ws + 4 * SEG);
  __bf16* Vpc = (__bf16*)((char*)d_ws + 5 * SEG);
  int* sel = (int*)((char*)d_ws + 7 * SEG);
  int* cnt = sel + B_ * L_;

  // Wb (96 KiB) in d_out scratch: wconv writes, proj reads, attn then
  // overwrites ALL of d_out — stream-ordered, race-free.
  __bf16* Wb = (__bf16*)((char*)d_out + (4u << 20));

  scan_kernel<<<B_, 256, 0, stream>>>(mask, sel, cnt);
  wconv_kernel<<<24, 256, 0, stream>>>(wmem, wq, Wb);
  proj_kernel<<<B_ * (L_ / 16), 256, 0, stream>>>(queries, mask, Wb, Qs, Ks, Vp);
  compact_kernel<<<B_ * H_ * 8, 256, 0, stream>>>(sel, cnt, Ks, Vp, Ksc, Vpc);
  attn_kernel<<<B_ * H_ * (L_ / 128), 256, 0, stream>>>(Qs, Ksc, Vpc, cnt, out);
}